// Round 1
// 5405.957 us; speedup vs baseline: 1.4277x; 1.4277x over previous
//
#include <hip/hip_runtime.h>
#include <math.h>

#define VOCAB 32000
#define SEQ 2048
#define NL 8
#define NH 16
#define DM 1024
#define DFF 4096
#define DH 64
#define NB 2
#define MM (NB*SEQ)   /* 4096 rows in the flattened [B*S, D] activation */

typedef __attribute__((ext_vector_type(4))) float f32x4;
typedef __attribute__((ext_vector_type(8))) short s16x8;

__device__ __forceinline__ ushort f2b(float f) {
  union { float f; unsigned u; } c; c.f = f;
  unsigned u = c.u;
  return (ushort)((u + 0x7fffu + ((u >> 16) & 1u)) >> 16);
}

__device__ __forceinline__ f32x4 mfma16(s16x8 a, s16x8 b, f32x4 c) {
  return __builtin_amdgcn_mfma_f32_16x16x32_bf16(a, b, c, 0, 0, 0);
}

__device__ __forceinline__ void gl_lds16(const ushort* g, ushort* l) {
  __builtin_amdgcn_global_load_lds((const __attribute__((address_space(1))) void*)g,
                                   (__attribute__((address_space(3))) void*)l, 16, 0, 0);
}

// ---------------- cast f32 -> bf16 (vectorized) ----------------
__global__ __launch_bounds__(256) void cast_kernel(const float* __restrict__ in,
                                                   ushort* __restrict__ out, int n4) {
  int i = blockIdx.x * 256 + threadIdx.x;
  if (i >= n4) return;
  float4 v = ((const float4*)in)[i];
  ushort4 o;
  o.x = f2b(v.x); o.y = f2b(v.y); o.z = f2b(v.z); o.w = f2b(v.w);
  ((ushort4*)out)[i] = o;
}

// ---------------- transpose + cast: in f32 [K,N] -> out bf16 [N,K], batched over z ----------------
#define TP 68
__global__ __launch_bounds__(256) void tcast_kernel(const float* __restrict__ in,
                                                    ushort* __restrict__ out,
                                                    int Kd, int Nd) {
  __shared__ ushort t[64 * TP];
  const long base = (long)blockIdx.z * Kd * Nd;
  const int k0 = blockIdx.y * 64, n0 = blockIdx.x * 64;
  const int tid = threadIdx.x;
  #pragma unroll
  for (int i = 0; i < 4; i++) {
    int idx = i * 256 + tid;
    int r = idx >> 4, c = (idx & 15) << 2;
    float4 v = *(const float4*)(in + base + (long)(k0 + r) * Nd + n0 + c);
    t[r * TP + c + 0] = f2b(v.x);
    t[r * TP + c + 1] = f2b(v.y);
    t[r * TP + c + 2] = f2b(v.z);
    t[r * TP + c + 3] = f2b(v.w);
  }
  __syncthreads();
  #pragma unroll
  for (int i = 0; i < 4; i++) {
    int idx = i * 256 + tid;
    int rr = idx >> 4, c = (idx & 15) << 2;
    ushort4 o;
    o.x = t[(c + 0) * TP + rr];
    o.y = t[(c + 1) * TP + rr];
    o.z = t[(c + 2) * TP + rr];
    o.w = t[(c + 3) * TP + rr];
    *(ushort4*)(out + base + (long)(n0 + rr) * Kd + k0 + c) = o;
  }
}

// ---------------- embedding: x = token_emb[id] + pos_emb ----------------
__global__ __launch_bounds__(256) void embed_kernel(const int* __restrict__ ids,
                                                    const float* __restrict__ emb,
                                                    const float* __restrict__ pos,
                                                    float* __restrict__ x) {
  const int row = blockIdx.x;            // b*SEQ + s
  const int s = row & (SEQ - 1);
  const int id = ids[row];
  const float4* e = (const float4*)(emb + (long)id * DM);
  const float4* p = (const float4*)(pos + (long)s * DM);
  float4* o = (float4*)(x + (long)row * DM);
  int c = threadIdx.x;                   // DM/4 == 256 == blockDim
  float4 a = e[c], b = p[c];
  float4 r; r.x = a.x + b.x; r.y = a.y + b.y; r.z = a.z + b.z; r.w = a.w + b.w;
  o[c] = r;
}

// ---------------- RMSNorm (f32 in, bf16 out) ----------------
__global__ __launch_bounds__(256) void rmsnorm_kernel(const float* __restrict__ x,
                                                      const float* __restrict__ w,
                                                      ushort* __restrict__ out) {
  const int row = blockIdx.x;
  const int t = threadIdx.x;
  float4 v = ((const float4*)(x + (long)row * DM))[t];
  float ss = v.x*v.x + v.y*v.y + v.z*v.z + v.w*v.w;
  #pragma unroll
  for (int m = 1; m < 64; m <<= 1) ss += __shfl_xor(ss, m);
  __shared__ float sm[4];
  if ((t & 63) == 0) sm[t >> 6] = ss;
  __syncthreads();
  float tot = sm[0] + sm[1] + sm[2] + sm[3];
  float rr = rsqrtf(tot * (1.0f / DM) + 1.1920929e-07f);   // torch eps=None -> f32 finfo eps
  float4 wv = ((const float4*)w)[t];
  ushort4 o;
  o.x = f2b(v.x * rr * wv.x); o.y = f2b(v.y * rr * wv.y);
  o.z = f2b(v.z * rr * wv.z); o.w = f2b(v.w * rr * wv.w);
  ((ushort4*)out)[(long)row * (DM/4) + t] = o;
}

// ---------------- GEMM: C[M,N] = A[M,K](bf16) @ B[N,K](bf16)^T ----------------
// All B operands are pre-transposed to [N,K] (k-contiguous), so both tiles stage
// linearly via global_load_lds (m97 structure: [128][32] LDS, width-16 DMA).
// MODE 0: f32 out (+XCD swizzle, logits). 1: f32 out + f32 residual.
// 2: bf16 out. 3: gelu(erf) -> bf16 out.
template<int MODE>
__global__ __launch_bounds__(256) void gemm_kernel(const ushort* __restrict__ A,
                                                   const ushort* __restrict__ Bm,
                                                   float* __restrict__ Cf,
                                                   ushort* __restrict__ Cb,
                                                   const float* __restrict__ R,
                                                   int Md, int Nd, int Kd) {
  __shared__ ushort sA[128 * 32];
  __shared__ ushort sB[128 * 32];
  const int tid = threadIdx.x;
  const int wave = tid >> 6, lane = tid & 63;
  const int quad = lane >> 4, l16 = lane & 15;
  const int wm = (wave >> 1) * 64, wn = (wave & 1) * 64;

  int bx = blockIdx.x, by = blockIdx.y;
  if (MODE == 0) {
    // XCD-aware bijective swizzle (nwg % 8 == 0 for our launches)
    int nwg = gridDim.x * gridDim.y;
    int b = by * gridDim.x + bx;
    int q = nwg >> 3;
    int s = (b & 7) * q + (b >> 3);
    bx = s % gridDim.x; by = s / gridDim.x;
  }
  const long m0 = (long)by * 128, n0 = (long)bx * 128;

  // per-wave staging: wave owns 32 rows; 2 DMA instrs of 16 rows each.
  // lane l -> row seg+l/4, k-halfword (l%4)*8  (matches linear LDS dest base+lane*16)
  const ushort* Ap = A + (m0 + wave * 32 + (lane >> 2)) * (long)Kd + ((lane & 3) << 3);
  const ushort* Bp = Bm + (n0 + wave * 32 + (lane >> 2)) * (long)Kd + ((lane & 3) << 3);
  ushort* sAw = sA + wave * 1024;
  ushort* sBw = sB + wave * 1024;
  const long rstep = 16 * (long)Kd;

  f32x4 acc[4][4];
  #pragma unroll
  for (int i = 0; i < 4; i++)
    #pragma unroll
    for (int j = 0; j < 4; j++) acc[i][j] = (f32x4){0.f, 0.f, 0.f, 0.f};

  for (long k0 = 0; k0 < Kd; k0 += 32) {
    __syncthreads();                       // prior tile's ds_reads done
    gl_lds16(Ap + k0, sAw);
    gl_lds16(Ap + k0 + rstep, sAw + 512);
    gl_lds16(Bp + k0, sBw);
    gl_lds16(Bp + k0 + rstep, sBw + 512);
    __syncthreads();                       // compiler drains vmcnt before barrier
    s16x8 af[4], bf[4];
    #pragma unroll
    for (int mi = 0; mi < 4; mi++)
      af[mi] = *(const s16x8*)(sA + (wm + mi*16 + l16) * 32 + quad * 8);
    #pragma unroll
    for (int ni = 0; ni < 4; ni++)
      bf[ni] = *(const s16x8*)(sB + (wn + ni*16 + l16) * 32 + quad * 8);
    #pragma unroll
    for (int mi = 0; mi < 4; mi++)
      #pragma unroll
      for (int ni = 0; ni < 4; ni++)
        acc[mi][ni] = mfma16(af[mi], bf[ni], acc[mi][ni]);
  }

  #pragma unroll
  for (int mi = 0; mi < 4; mi++) {
    #pragma unroll
    for (int ni = 0; ni < 4; ni++) {
      #pragma unroll
      for (int r = 0; r < 4; r++) {
        long row = m0 + wm + mi*16 + quad*4 + r;
        long col = n0 + wn + ni*16 + l16;
        float v = acc[mi][ni][r];
        if (MODE == 0) {
          Cf[row * Nd + col] = v;
        } else if (MODE == 1) {
          Cf[row * Nd + col] = v + R[row * Nd + col];
        } else if (MODE == 2) {
          Cb[row * Nd + col] = f2b(v);
        } else {
          float g = 0.5f * v * (1.0f + erff(v * 0.70710678118654752f));
          Cb[row * Nd + col] = f2b(g);
        }
      }
    }
  }
}

// ---------------- flash attention (causal, online softmax) ----------------
// grid: (SEQ/64, NB*NH); each wave owns 16 q rows, iterates 32-key tiles.
__global__ __launch_bounds__(256) void attn_kernel(const ushort* __restrict__ Q,
                                                   const ushort* __restrict__ K,
                                                   const ushort* __restrict__ Vv,
                                                   ushort* __restrict__ O) {
  __shared__ ushort sP[4 * 16 * 32];   // per-wave 16x32 P tile
  const int wave = threadIdx.x >> 6, lane = threadIdx.x & 63;
  const int quad = lane >> 4, l16 = lane & 15;
  const int bh = blockIdx.y, b = bh >> 4, h = bh & 15;
  const int qb = blockIdx.x * 64 + wave * 16;
  const long rowbase = (long)b * SEQ;
  const int colbase = h * DH;

  const ushort* qp = Q + (rowbase + qb + l16) * (long)DM + colbase;
  s16x8 aq0 = *(const s16x8*)(qp + quad * 8);
  s16x8 aq1 = *(const s16x8*)(qp + 32 + quad * 8);

  f32x4 oacc[4];
  #pragma unroll
  for (int f = 0; f < 4; f++) oacc[f] = (f32x4){0.f, 0.f, 0.f, 0.f};
  float mr[4] = {-3.0e38f, -3.0e38f, -3.0e38f, -3.0e38f};
  float lr[4] = {0.f, 0.f, 0.f, 0.f};
  const f32x4 zero = (f32x4){0.f, 0.f, 0.f, 0.f};

  for (int kb = 0; kb <= qb + 15; kb += 32) {
    f32x4 sacc[2];
    #pragma unroll
    for (int c = 0; c < 2; c++) {
      const ushort* kp = K + (rowbase + kb + c*16 + l16) * (long)DM + colbase;
      s16x8 bk0 = *(const s16x8*)(kp + quad * 8);
      s16x8 bk1 = *(const s16x8*)(kp + 32 + quad * 8);
      sacc[c] = mfma16(aq0, bk0, zero);
      sacc[c] = mfma16(aq1, bk1, sacc[c]);
    }
    float p[2][4];
    #pragma unroll
    for (int r = 0; r < 4; r++) {
      int qrow = qb + quad*4 + r;
      #pragma unroll
      for (int c = 0; c < 2; c++) {
        int kcol = kb + c*16 + l16;
        float sv = sacc[c][r] * 0.125f;          // 1/sqrt(64)
        if (kcol > qrow) sv = -3.0e38f;          // causal mask
        p[c][r] = sv;
      }
      float t = fmaxf(p[0][r], p[1][r]);
      t = fmaxf(t, __shfl_xor(t, 1));
      t = fmaxf(t, __shfl_xor(t, 2));
      t = fmaxf(t, __shfl_xor(t, 4));
      t = fmaxf(t, __shfl_xor(t, 8));
      float newm = fmaxf(mr[r], t);
      float alpha = __expf(mr[r] - newm);
      mr[r] = newm;
      float pv0 = __expf(p[0][r] - newm);
      float pv1 = __expf(p[1][r] - newm);
      p[0][r] = pv0; p[1][r] = pv1;
      float rs = pv0 + pv1;
      rs += __shfl_xor(rs, 1);
      rs += __shfl_xor(rs, 2);
      rs += __shfl_xor(rs, 4);
      rs += __shfl_xor(rs, 8);
      lr[r] = lr[r] * alpha + rs;
      #pragma unroll
      for (int f = 0; f < 4; f++) oacc[f][r] *= alpha;
    }
    // P: C-layout -> LDS -> A-layout (per-wave region; no cross-wave sync)
    #pragma unroll
    for (int r = 0; r < 4; r++)
      #pragma unroll
      for (int c = 0; c < 2; c++)
        sP[wave * 512 + (quad*4 + r) * 32 + c*16 + l16] = f2b(p[c][r]);
    s16x8 ap = *(const s16x8*)(&sP[wave * 512 + l16 * 32 + quad * 8]);
    #pragma unroll
    for (int f = 0; f < 4; f++) {
      s16x8 bv;
      #pragma unroll
      for (int j = 0; j < 8; j++)
        bv[j] = (short)Vv[(rowbase + kb + quad*8 + j) * (long)DM + colbase + f*16 + l16];
      oacc[f] = mfma16(ap, bv, oacc[f]);
    }
  }
  #pragma unroll
  for (int f = 0; f < 4; f++) {
    #pragma unroll
    for (int r = 0; r < 4; r++) {
      long row = rowbase + qb + quad*4 + r;
      float inv = 1.0f / lr[r];
      O[row * (long)DM + colbase + f*16 + l16] = f2b(oacc[f][r] * inv);
    }
  }
}

// ---------------- host ----------------
extern "C" void kernel_launch(void* const* d_in, const int* in_sizes, int n_in,
                              void* d_out, int out_size, void* d_ws, size_t ws_size,
                              hipStream_t stream) {
  const int*   ids  = (const int*)d_in[0];
  const float* temb = (const float*)d_in[1];
  const float* pemb = (const float*)d_in[2];
  const float* wq   = (const float*)d_in[3];
  const float* wk   = (const float*)d_in[4];
  const float* wv   = (const float*)d_in[5];
  const float* wo   = (const float*)d_in[6];
  const float* w1   = (const float*)d_in[7];
  const float* w2   = (const float*)d_in[8];
  const float* anw  = (const float*)d_in[9];
  const float* fnw  = (const float*)d_in[10];
  const float* finw = (const float*)d_in[11];
  float* logits = (float*)d_out;

  char* p = (char*)d_ws;
  auto take = [&](size_t n) { char* r = p; p += (n + 255) & ~(size_t)255; return r; };
  ushort* wq_b = (ushort*)take((size_t)NL*DM*DM*2);   // transposed [N,K] per layer
  ushort* wk_b = (ushort*)take((size_t)NL*DM*DM*2);
  ushort* wv_b = (ushort*)take((size_t)NL*DM*DM*2);
  ushort* wo_b = (ushort*)take((size_t)NL*DM*DM*2);
  ushort* w1_b = (ushort*)take((size_t)NL*DM*DFF*2);  // [DFF,DM] per layer
  ushort* w2_b = (ushort*)take((size_t)NL*DFF*DM*2);  // [DM,DFF] per layer
  ushort* te_b = (ushort*)take((size_t)VOCAB*DM*2);   // [V,DM] already k-contig
  float*  x    = (float*) take((size_t)MM*DM*4);
  ushort* hb   = (ushort*)take((size_t)MM*DM*2);
  ushort* qbuf = (ushort*)take((size_t)MM*DM*2);
  ushort* kbuf = (ushort*)take((size_t)MM*DM*2);
  ushort* vbuf = (ushort*)take((size_t)MM*DM*2);
  ushort* abuf = (ushort*)take((size_t)MM*DM*2);
  ushort* gbuf = (ushort*)take((size_t)MM*DFF*2);

  // weights: fused transpose+cast to [N,K] bf16 (per layer batch in z)
  tcast_kernel<<<dim3(DM/64,  DM/64,  NL), 256, 0, stream>>>(wq, wq_b, DM, DM);
  tcast_kernel<<<dim3(DM/64,  DM/64,  NL), 256, 0, stream>>>(wk, wk_b, DM, DM);
  tcast_kernel<<<dim3(DM/64,  DM/64,  NL), 256, 0, stream>>>(wv, wv_b, DM, DM);
  tcast_kernel<<<dim3(DM/64,  DM/64,  NL), 256, 0, stream>>>(wo, wo_b, DM, DM);
  tcast_kernel<<<dim3(DFF/64, DM/64,  NL), 256, 0, stream>>>(w1, w1_b, DM, DFF);
  tcast_kernel<<<dim3(DM/64,  DFF/64, NL), 256, 0, stream>>>(w2, w2_b, DFF, DM);
  {
    int n4 = (int)((size_t)VOCAB*DM / 4);
    cast_kernel<<<(n4 + 255) / 256, 256, 0, stream>>>(temb, te_b, n4);
  }

  embed_kernel<<<MM, 256, 0, stream>>>(ids, temb, pemb, x);

  dim3 gQ(DM/128, MM/128);
  dim3 gF(DFF/128, MM/128);
  for (int l = 0; l < NL; l++) {
    size_t o1 = (size_t)l * DM * DM, o2 = (size_t)l * DM * DFF;
    rmsnorm_kernel<<<MM, 256, 0, stream>>>(x, anw + (size_t)l*DM, hb);
    gemm_kernel<2><<<gQ, 256, 0, stream>>>(hb, wq_b + o1, nullptr, qbuf, nullptr, MM, DM, DM);
    gemm_kernel<2><<<gQ, 256, 0, stream>>>(hb, wk_b + o1, nullptr, kbuf, nullptr, MM, DM, DM);
    gemm_kernel<2><<<gQ, 256, 0, stream>>>(hb, wv_b + o1, nullptr, vbuf, nullptr, MM, DM, DM);
    attn_kernel<<<dim3(SEQ/64, NB*NH), 256, 0, stream>>>(qbuf, kbuf, vbuf, abuf);
    gemm_kernel<1><<<gQ, 256, 0, stream>>>(abuf, wo_b + o1, x, nullptr, x, MM, DM, DM);
    rmsnorm_kernel<<<MM, 256, 0, stream>>>(x, fnw + (size_t)l*DM, hb);
    gemm_kernel<3><<<gF, 256, 0, stream>>>(hb, w1_b + o2, nullptr, gbuf, nullptr, MM, DFF, DM);
    gemm_kernel<1><<<gQ, 256, 0, stream>>>(gbuf, w2_b + o2, x, nullptr, x, MM, DM, DFF);
  }
  rmsnorm_kernel<<<MM, 256, 0, stream>>>(x, finw, hb);
  gemm_kernel<0><<<dim3(VOCAB/128, MM/128), 256, 0, stream>>>(hb, te_b, logits, nullptr, nullptr, MM, VOCAB, DM);
}

// Round 2
// 5032.195 us; speedup vs baseline: 1.5338x; 1.0743x over previous
//
#include <hip/hip_runtime.h>
#include <math.h>

#define VOCAB 32000
#define SEQ 2048
#define NL 8
#define NH 16
#define DM 1024
#define DFF 4096
#define DH 64
#define NB 2
#define MM (NB*SEQ)   /* 4096 rows in the flattened [B*S, D] activation */

typedef __attribute__((ext_vector_type(4))) float f32x4;
typedef __attribute__((ext_vector_type(8))) short s16x8;

__device__ __forceinline__ ushort f2b(float f) {
  union { float f; unsigned u; } c; c.f = f;
  unsigned u = c.u;
  return (ushort)((u + 0x7fffu + ((u >> 16) & 1u)) >> 16);
}

__device__ __forceinline__ f32x4 mfma16(s16x8 a, s16x8 b, f32x4 c) {
  return __builtin_amdgcn_mfma_f32_16x16x32_bf16(a, b, c, 0, 0, 0);
}

__device__ __forceinline__ void gl_lds16(const ushort* g, ushort* l) {
  __builtin_amdgcn_global_load_lds((const __attribute__((address_space(1))) void*)g,
                                   (__attribute__((address_space(3))) void*)l, 16, 0, 0);
}

// ---------------- cast f32 -> bf16 (vectorized) ----------------
__global__ __launch_bounds__(256) void cast_kernel(const float* __restrict__ in,
                                                   ushort* __restrict__ out, int n4) {
  int i = blockIdx.x * 256 + threadIdx.x;
  if (i >= n4) return;
  float4 v = ((const float4*)in)[i];
  ushort4 o;
  o.x = f2b(v.x); o.y = f2b(v.y); o.z = f2b(v.z); o.w = f2b(v.w);
  ((ushort4*)out)[i] = o;
}

// ---------------- transpose + cast: in f32 [K,N] -> out bf16 [N,K], batched over z ----------------
// Separate layer strides so multiple weight sections can pack into one [N,K] buffer.
#define TP 68
__global__ __launch_bounds__(256) void tcast_kernel(const float* __restrict__ in,
                                                    ushort* __restrict__ out,
                                                    int Kd, int Nd,
                                                    long inLS, long outLS) {
  __shared__ ushort t[64 * TP];
  const float* ip = in + (long)blockIdx.z * inLS;
  ushort* op = out + (long)blockIdx.z * outLS;
  const int k0 = blockIdx.y * 64, n0 = blockIdx.x * 64;
  const int tid = threadIdx.x;
  #pragma unroll
  for (int i = 0; i < 4; i++) {
    int idx = i * 256 + tid;
    int r = idx >> 4, c = (idx & 15) << 2;
    float4 v = *(const float4*)(ip + (long)(k0 + r) * Nd + n0 + c);
    t[r * TP + c + 0] = f2b(v.x);
    t[r * TP + c + 1] = f2b(v.y);
    t[r * TP + c + 2] = f2b(v.z);
    t[r * TP + c + 3] = f2b(v.w);
  }
  __syncthreads();
  #pragma unroll
  for (int i = 0; i < 4; i++) {
    int idx = i * 256 + tid;
    int rr = idx >> 4, c = (idx & 15) << 2;
    ushort4 o;
    o.x = t[(c + 0) * TP + rr];
    o.y = t[(c + 1) * TP + rr];
    o.z = t[(c + 2) * TP + rr];
    o.w = t[(c + 3) * TP + rr];
    *(ushort4*)(op + (long)(n0 + rr) * Kd + k0 + c) = o;
  }
}

// ---------------- embedding: x = token_emb[id] + pos_emb ----------------
__global__ __launch_bounds__(256) void embed_kernel(const int* __restrict__ ids,
                                                    const float* __restrict__ emb,
                                                    const float* __restrict__ pos,
                                                    float* __restrict__ x) {
  const int row = blockIdx.x;            // b*SEQ + s
  const int s = row & (SEQ - 1);
  const int id = ids[row];
  const float4* e = (const float4*)(emb + (long)id * DM);
  const float4* p = (const float4*)(pos + (long)s * DM);
  float4* o = (float4*)(x + (long)row * DM);
  int c = threadIdx.x;                   // DM/4 == 256 == blockDim
  float4 a = e[c], b = p[c];
  float4 r; r.x = a.x + b.x; r.y = a.y + b.y; r.z = a.z + b.z; r.w = a.w + b.w;
  o[c] = r;
}

// ---------------- RMSNorm (f32 in, bf16 out) ----------------
__global__ __launch_bounds__(256) void rmsnorm_kernel(const float* __restrict__ x,
                                                      const float* __restrict__ w,
                                                      ushort* __restrict__ out) {
  const int row = blockIdx.x;
  const int t = threadIdx.x;
  float4 v = ((const float4*)(x + (long)row * DM))[t];
  float ss = v.x*v.x + v.y*v.y + v.z*v.z + v.w*v.w;
  #pragma unroll
  for (int m = 1; m < 64; m <<= 1) ss += __shfl_xor(ss, m);
  __shared__ float sm[4];
  if ((t & 63) == 0) sm[t >> 6] = ss;
  __syncthreads();
  float tot = sm[0] + sm[1] + sm[2] + sm[3];
  float rr = rsqrtf(tot * (1.0f / DM) + 1.1920929e-07f);   // torch eps=None -> f32 finfo eps
  float4 wv = ((const float4*)w)[t];
  ushort4 o;
  o.x = f2b(v.x * rr * wv.x); o.y = f2b(v.y * rr * wv.y);
  o.z = f2b(v.z * rr * wv.z); o.w = f2b(v.w * rr * wv.w);
  ((ushort4*)out)[(long)row * (DM/4) + t] = o;
}

// ---------------- GEMM: C[M,N] = A[M,K](bf16) @ B[N,K](bf16)^T ----------------
// 2-phase double-buffered: stage tile k+1 via global_load_lds BEFORE computing
// tile k; single barrier per K-step so DMA latency hides under MFMA.
// MODE 0: f32 out + XCD swizzle (logits). 1: f32 out + f32 residual.
// 3: gelu(erf) -> bf16 out. 5: fused-QKV split store (Q,K -> Cb [M,2048];
//    V -> Ct transposed [DM][MM] for the attention PV B-fragment).
template<int MODE>
__global__ __launch_bounds__(256) void gemm_kernel(const ushort* __restrict__ A,
                                                   const ushort* __restrict__ Bm,
                                                   float* __restrict__ Cf,
                                                   ushort* __restrict__ Cb,
                                                   ushort* __restrict__ Ct,
                                                   const float* __restrict__ R,
                                                   int Md, int Nd, int Kd) {
  __shared__ ushort sA[2][128 * 32];
  __shared__ ushort sB[2][128 * 32];
  const int tid = threadIdx.x;
  const int wave = tid >> 6, lane = tid & 63;
  const int quad = lane >> 4, l16 = lane & 15;
  const int wm = (wave >> 1) * 64, wn = (wave & 1) * 64;

  int bx = blockIdx.x, by = blockIdx.y;
  if (MODE == 0) {
    // XCD-aware bijective swizzle (nwg % 8 == 0 for our launches)
    int nwg = gridDim.x * gridDim.y;
    int b = by * gridDim.x + bx;
    int q = nwg >> 3;
    int s = (b & 7) * q + (b >> 3);
    bx = s % gridDim.x; by = s / gridDim.x;
  }
  const long m0 = (long)by * 128, n0 = (long)bx * 128;

  // per-wave staging: wave owns 32 rows; 2 DMA instrs of 16 rows each.
  const ushort* Ap = A + (m0 + wave * 32 + (lane >> 2)) * (long)Kd + ((lane & 3) << 3);
  const ushort* Bp = Bm + (n0 + wave * 32 + (lane >> 2)) * (long)Kd + ((lane & 3) << 3);
  const int ldso = wave * 1024;
  const long rstep = 16 * (long)Kd;

  auto stage = [&](int buf, long k0) {
    gl_lds16(Ap + k0, &sA[buf][ldso]);
    gl_lds16(Ap + k0 + rstep, &sA[buf][ldso + 512]);
    gl_lds16(Bp + k0, &sB[buf][ldso]);
    gl_lds16(Bp + k0 + rstep, &sB[buf][ldso + 512]);
  };

  f32x4 acc[4][4];
  #pragma unroll
  for (int i = 0; i < 4; i++)
    #pragma unroll
    for (int j = 0; j < 4; j++) acc[i][j] = (f32x4){0.f, 0.f, 0.f, 0.f};

  stage(0, 0);
  __syncthreads();
  int cur = 0;
  for (long k0 = 0; k0 < Kd; k0 += 32) {
    if (k0 + 32 < Kd) stage(cur ^ 1, k0 + 32);
    s16x8 af[4], bf[4];
    #pragma unroll
    for (int mi = 0; mi < 4; mi++)
      af[mi] = *(const s16x8*)(&sA[cur][(wm + mi*16 + l16) * 32 + quad * 8]);
    #pragma unroll
    for (int ni = 0; ni < 4; ni++)
      bf[ni] = *(const s16x8*)(&sB[cur][(wn + ni*16 + l16) * 32 + quad * 8]);
    #pragma unroll
    for (int mi = 0; mi < 4; mi++)
      #pragma unroll
      for (int ni = 0; ni < 4; ni++)
        acc[mi][ni] = mfma16(af[mi], bf[ni], acc[mi][ni]);
    __syncthreads();   // drains stage DMA (vmcnt) + this tile's ds_reads (lgkm)
    cur ^= 1;
  }

  if (MODE == 5 && n0 >= 2048) {
    // V section: transposed bf16 store Vt[d][token], packed 4 rows per store
    #pragma unroll
    for (int mi = 0; mi < 4; mi++) {
      #pragma unroll
      for (int ni = 0; ni < 4; ni++) {
        long d = n0 + wn + ni*16 + l16 - 2048;
        long row0 = m0 + wm + mi*16 + quad*4;
        ushort4 o;
        o.x = f2b(acc[mi][ni][0]); o.y = f2b(acc[mi][ni][1]);
        o.z = f2b(acc[mi][ni][2]); o.w = f2b(acc[mi][ni][3]);
        *(ushort4*)(Ct + d * MM + row0) = o;
      }
    }
    return;
  }

  #pragma unroll
  for (int mi = 0; mi < 4; mi++) {
    #pragma unroll
    for (int ni = 0; ni < 4; ni++) {
      #pragma unroll
      for (int r = 0; r < 4; r++) {
        long row = m0 + wm + mi*16 + quad*4 + r;
        long col = n0 + wn + ni*16 + l16;
        float v = acc[mi][ni][r];
        if (MODE == 0) {
          Cf[row * Nd + col] = v;
        } else if (MODE == 1) {
          Cf[row * Nd + col] = v + R[row * Nd + col];
        } else if (MODE == 3) {
          float g = 0.5f * v * (1.0f + erff(v * 0.70710678118654752f));
          Cb[row * Nd + col] = f2b(g);
        } else if (MODE == 5) {
          Cb[row * 2048 + col] = f2b(v);   // Q,K section
        }
      }
    }
  }
}

// ---------------- flash attention (causal, online softmax) ----------------
// grid: (SEQ/64, NB*NH); each wave owns 16 q rows, iterates 64-key tiles.
// Q,K from fused qk buffer [MM][2048]; V from transposed Vt [DM][MM] so the
// PV B-fragment is a contiguous s16x8 load.
#define SPLD 72   /* padded P-tile row: 144 B -> 2-way (free) b128 reads */
__global__ __launch_bounds__(256) void attn_kernel(const ushort* __restrict__ QK,
                                                   const ushort* __restrict__ Vt,
                                                   ushort* __restrict__ O) {
  __shared__ ushort sP[4 * 16 * SPLD];
  const int wave = threadIdx.x >> 6, lane = threadIdx.x & 63;
  const int quad = lane >> 4, l16 = lane & 15;
  const int bh = blockIdx.y, b = bh >> 4, h = bh & 15;
  const int qb = blockIdx.x * 64 + wave * 16;
  const long rowbase = (long)b * SEQ;
  const int colbase = h * DH;
  ushort* sPw = sP + wave * 16 * SPLD;

  const ushort* qp = QK + (rowbase + qb + l16) * 2048 + colbase;
  s16x8 aq0 = *(const s16x8*)(qp + quad * 8);
  s16x8 aq1 = *(const s16x8*)(qp + 32 + quad * 8);

  f32x4 oacc[4];
  #pragma unroll
  for (int f = 0; f < 4; f++) oacc[f] = (f32x4){0.f, 0.f, 0.f, 0.f};
  float mr[4] = {-3.0e38f, -3.0e38f, -3.0e38f, -3.0e38f};
  float lr[4] = {0.f, 0.f, 0.f, 0.f};
  const f32x4 zero = (f32x4){0.f, 0.f, 0.f, 0.f};

  for (int kb = 0; kb <= qb + 15; kb += 64) {
    // ---- QK^T over 64 keys (4 16-col chunks) ----
    f32x4 sacc[4];
    #pragma unroll
    for (int c = 0; c < 4; c++) {
      const ushort* kp = QK + (rowbase + kb + c*16 + l16) * 2048 + 1024 + colbase;
      s16x8 bk0 = *(const s16x8*)(kp + quad * 8);
      s16x8 bk1 = *(const s16x8*)(kp + 32 + quad * 8);
      sacc[c] = mfma16(aq0, bk0, zero);
      sacc[c] = mfma16(aq1, bk1, sacc[c]);
    }
    // ---- online softmax, one pass over the 64-key tile ----
    float p[4][4];   // [c][r]
    #pragma unroll
    for (int r = 0; r < 4; r++) {
      int qrow = qb + quad*4 + r;
      #pragma unroll
      for (int c = 0; c < 4; c++) {
        int kcol = kb + c*16 + l16;
        float sv = sacc[c][r] * 0.125f;          // 1/sqrt(64)
        p[c][r] = (kcol > qrow) ? -3.0e38f : sv; // causal mask
      }
      float t = fmaxf(fmaxf(p[0][r], p[1][r]), fmaxf(p[2][r], p[3][r]));
      t = fmaxf(t, __shfl_xor(t, 1));
      t = fmaxf(t, __shfl_xor(t, 2));
      t = fmaxf(t, __shfl_xor(t, 4));
      t = fmaxf(t, __shfl_xor(t, 8));
      float newm = fmaxf(mr[r], t);
      float alpha = __expf(mr[r] - newm);
      mr[r] = newm;
      float rs = 0.f;
      #pragma unroll
      for (int c = 0; c < 4; c++) { p[c][r] = __expf(p[c][r] - newm); rs += p[c][r]; }
      rs += __shfl_xor(rs, 1);
      rs += __shfl_xor(rs, 2);
      rs += __shfl_xor(rs, 4);
      rs += __shfl_xor(rs, 8);
      lr[r] = lr[r] * alpha + rs;
      #pragma unroll
      for (int f = 0; f < 4; f++) oacc[f][r] *= alpha;
      #pragma unroll
      for (int c = 0; c < 4; c++)
        sPw[(quad*4 + r) * SPLD + c*16 + l16] = f2b(p[c][r]);
    }
    // P: C-layout -> LDS -> A-layout (per-wave region; in-order DS per wave)
    s16x8 ap0 = *(const s16x8*)(&sPw[l16 * SPLD + quad * 8]);
    s16x8 ap1 = *(const s16x8*)(&sPw[l16 * SPLD + 32 + quad * 8]);
    // ---- PV: B-fragment = contiguous 8 ushorts of Vt ----
    #pragma unroll
    for (int f = 0; f < 4; f++) {
      const ushort* vp = Vt + (long)(colbase + f*16 + l16) * MM + rowbase + kb + quad*8;
      s16x8 bv0 = *(const s16x8*)(vp);
      s16x8 bv1 = *(const s16x8*)(vp + 32);
      oacc[f] = mfma16(ap0, bv0, oacc[f]);
      oacc[f] = mfma16(ap1, bv1, oacc[f]);
    }
  }
  #pragma unroll
  for (int f = 0; f < 4; f++) {
    #pragma unroll
    for (int r = 0; r < 4; r++) {
      long row = rowbase + qb + quad*4 + r;
      float inv = 1.0f / lr[r];
      O[row * (long)DM + colbase + f*16 + l16] = f2b(oacc[f][r] * inv);
    }
  }
}

// ---------------- host ----------------
extern "C" void kernel_launch(void* const* d_in, const int* in_sizes, int n_in,
                              void* d_out, int out_size, void* d_ws, size_t ws_size,
                              hipStream_t stream) {
  const int*   ids  = (const int*)d_in[0];
  const float* temb = (const float*)d_in[1];
  const float* pemb = (const float*)d_in[2];
  const float* wq   = (const float*)d_in[3];
  const float* wk   = (const float*)d_in[4];
  const float* wv   = (const float*)d_in[5];
  const float* wo   = (const float*)d_in[6];
  const float* w1   = (const float*)d_in[7];
  const float* w2   = (const float*)d_in[8];
  const float* anw  = (const float*)d_in[9];
  const float* fnw  = (const float*)d_in[10];
  const float* finw = (const float*)d_in[11];
  float* logits = (float*)d_out;

  char* p = (char*)d_ws;
  auto take = [&](size_t n) { char* r = p; p += (n + 255) & ~(size_t)255; return r; };
  ushort* wqkv_b = (ushort*)take((size_t)NL*3*DM*DM*2); // [3072,1024] per layer (q|k|v rows)
  ushort* wo_b   = (ushort*)take((size_t)NL*DM*DM*2);   // [N,K]
  ushort* w1_b   = (ushort*)take((size_t)NL*DM*DFF*2);  // [DFF,DM]
  ushort* w2_b   = (ushort*)take((size_t)NL*DFF*DM*2);  // [DM,DFF]
  ushort* te_b   = (ushort*)take((size_t)VOCAB*DM*2);   // [V,DM] already k-contig
  float*  x      = (float*) take((size_t)MM*DM*4);
  ushort* hb     = (ushort*)take((size_t)MM*DM*2);
  ushort* qkbuf  = (ushort*)take((size_t)MM*2*DM*2);    // [MM][2048] Q|K
  ushort* vtbuf  = (ushort*)take((size_t)DM*MM*2);      // [DM][MM] V^T
  ushort* abuf   = (ushort*)take((size_t)MM*DM*2);
  ushort* gbuf   = (ushort*)take((size_t)MM*DFF*2);

  // weights: fused transpose+cast to [N,K] bf16 (layer batch in z)
  const long LQ = (long)DM*DM, L3 = (long)3*DM*DM, LF = (long)DM*DFF;
  tcast_kernel<<<dim3(DM/64,  DM/64,  NL), 256, 0, stream>>>(wq, wqkv_b,             DM, DM, LQ, L3);
  tcast_kernel<<<dim3(DM/64,  DM/64,  NL), 256, 0, stream>>>(wk, wqkv_b + (long)DM*DM,   DM, DM, LQ, L3);
  tcast_kernel<<<dim3(DM/64,  DM/64,  NL), 256, 0, stream>>>(wv, wqkv_b + (long)2*DM*DM, DM, DM, LQ, L3);
  tcast_kernel<<<dim3(DM/64,  DM/64,  NL), 256, 0, stream>>>(wo, wo_b, DM, DM, LQ, LQ);
  tcast_kernel<<<dim3(DFF/64, DM/64,  NL), 256, 0, stream>>>(w1, w1_b, DM, DFF, LF, LF);
  tcast_kernel<<<dim3(DM/64,  DFF/64, NL), 256, 0, stream>>>(w2, w2_b, DFF, DM, LF, LF);
  {
    int n4 = (int)((size_t)VOCAB*DM / 4);
    cast_kernel<<<(n4 + 255) / 256, 256, 0, stream>>>(temb, te_b, n4);
  }

  embed_kernel<<<MM, 256, 0, stream>>>(ids, temb, pemb, x);

  dim3 gQKV(3*DM/128, MM/128);   // 24 x 32 = 768 blocks
  dim3 gQ(DM/128, MM/128);       // 8 x 32
  dim3 gF(DFF/128, MM/128);      // 32 x 32
  for (int l = 0; l < NL; l++) {
    size_t o3 = (size_t)l * 3*DM*DM, o1 = (size_t)l * DM * DM, o2 = (size_t)l * DM * DFF;
    rmsnorm_kernel<<<MM, 256, 0, stream>>>(x, anw + (size_t)l*DM, hb);
    gemm_kernel<5><<<gQKV, 256, 0, stream>>>(hb, wqkv_b + o3, nullptr, qkbuf, vtbuf, nullptr, MM, 3*DM, DM);
    attn_kernel<<<dim3(SEQ/64, NB*NH), 256, 0, stream>>>(qkbuf, vtbuf, abuf);
    gemm_kernel<1><<<gQ, 256, 0, stream>>>(abuf, wo_b + o1, x, nullptr, nullptr, x, MM, DM, DM);
    rmsnorm_kernel<<<MM, 256, 0, stream>>>(x, fnw + (size_t)l*DM, hb);
    gemm_kernel<3><<<gF, 256, 0, stream>>>(hb, w1_b + o2, nullptr, gbuf, nullptr, nullptr, MM, DFF, DM);
    gemm_kernel<1><<<gQ, 256, 0, stream>>>(gbuf, w2_b + o2, x, nullptr, nullptr, x, MM, DM, DFF);
  }
  rmsnorm_kernel<<<MM, 256, 0, stream>>>(x, finw, hb);
  gemm_kernel<0><<<dim3(VOCAB/128, MM/128), 256, 0, stream>>>(hb, te_b, logits, nullptr, nullptr, nullptr, MM, VOCAB, DM);
}